// Round 1
// baseline (352.985 us; speedup 1.0000x reference)
//
#include <hip/hip_runtime.h>

// Fused attention: Q/K/V = x@W^T + b (fp16 MFMA), S = mask(QK^T/32), P = softmax(S), O = P@V.
// B=4, S=2048, D=1024 (single head). All GEMMs are NT (both operands K-contiguous),
// m97-style: 128x128 block tile, 4 waves, 4x4 16x16x32 MFMA per wave, BK=32,
// global_load_lds width=16 staging.

typedef _Float16 f16;
typedef _Float16 f16x4 __attribute__((ext_vector_type(4)));
typedef _Float16 f16x8 __attribute__((ext_vector_type(8)));
typedef float f32x4 __attribute__((ext_vector_type(4)));

#define LB256 __launch_bounds__(256)

__device__ __forceinline__ void gld16(const void* gp, void* lp) {
  __builtin_amdgcn_global_load_lds(
      (__attribute__((address_space(1))) void*)(gp),
      (__attribute__((address_space(3))) void*)(lp),
      16, 0, 0);
}

// ---------------------------------------------------------------- NT GEMM
// C[m,n] = scale * sum_k A[m,k]*B[n,k] + bias[n]
// A: [M,K] f16 row-major (lda), B: [N,K] f16 row-major (ldb), C: OutT (ldc).
// Grid: (N/128, M/128, batch). Block: 256.
template <typename OutT>
__global__ LB256 void gemm_nt(
    const f16* __restrict__ A, int lda, long sA,
    const f16* __restrict__ B, int ldb, long sB,
    OutT* __restrict__ C, int ldc, long sC,
    const float* __restrict__ bias, float scale, int K) {
  __shared__ f16 As[128 * 32];
  __shared__ f16 Bs[128 * 32];
  A += (long)blockIdx.z * sA;
  B += (long)blockIdx.z * sB;
  C += (long)blockIdx.z * sC;
  const int m0 = blockIdx.y * 128;
  const int n0 = blockIdx.x * 128;
  const int tid = threadIdx.x;
  const int w = tid >> 6, l = tid & 63;
  const int wm = (w >> 1) * 64;  // wave row offset in tile
  const int wn = (w & 1) * 64;   // wave col offset in tile
  const int quad = l >> 4, lo = l & 15;
  const int srow = l >> 2;        // staging: row within 16-row chunk
  const int scol = (l & 3) * 8;   // staging: f16 offset (16B granules)

  f32x4 acc[4][4] = {};

  for (int kk = 0; kk < K; kk += 32) {
    // Stage A-tile [128][32] and B-tile [128][32] (8KB each) via global_load_lds.
    // Chunk c = r*4+w covers rows [c*16, c*16+16); LDS dest is wave-uniform base,
    // lane i lands at base + i*16B == row-major [c*16 + i/4][(i%4)*8] (f16).
#pragma unroll
    for (int r = 0; r < 2; ++r) {
      const int c = r * 4 + w;
      const int row = c * 16 + srow;
      gld16(A + (long)(m0 + row) * lda + kk + scol, &As[c * 512]);
      gld16(B + (long)(n0 + row) * ldb + kk + scol, &Bs[c * 512]);
    }
    __syncthreads();  // compiler emits vmcnt(0) drain before barrier
    f16x8 af[4], bf[4];
#pragma unroll
    for (int i = 0; i < 4; ++i)
      af[i] = *(const f16x8*)&As[(wm + i * 16 + lo) * 32 + quad * 8];
#pragma unroll
    for (int j = 0; j < 4; ++j)
      bf[j] = *(const f16x8*)&Bs[(wn + j * 16 + lo) * 32 + quad * 8];
#pragma unroll
    for (int i = 0; i < 4; ++i)
#pragma unroll
      for (int j = 0; j < 4; ++j)
        acc[i][j] =
            __builtin_amdgcn_mfma_f32_16x16x32_f16(af[i], bf[j], acc[i][j], 0, 0, 0);
    __syncthreads();
  }
  // Epilogue: C/D layout col=lane&15, row=quad*4+reg (m89-verified).
#pragma unroll
  for (int i = 0; i < 4; ++i) {
    const int rowb = m0 + wm + i * 16 + quad * 4;
#pragma unroll
    for (int j = 0; j < 4; ++j) {
      const int col = n0 + wn + j * 16 + lo;
      const float bv = bias ? bias[col] : 0.0f;
#pragma unroll
      for (int r = 0; r < 4; ++r)
        C[(long)(rowb + r) * ldc + col] = (OutT)(acc[i][j][r] * scale + bv);
    }
  }
}

// ---------------------------------------------------------------- casts
__global__ LB256 void f32_to_f16_x4(const float* __restrict__ in,
                                    f16* __restrict__ out, long n) {
  long i = ((long)blockIdx.x * 256 + threadIdx.x) * 4;
  if (i + 3 < n) {
    float4 v = *(const float4*)(in + i);
    f16x4 o;
    o[0] = (f16)v.x; o[1] = (f16)v.y; o[2] = (f16)v.z; o[3] = (f16)v.w;
    *(f16x4*)(out + i) = o;
  }
}

__global__ void concat_bias(const float* __restrict__ a, const float* __restrict__ b,
                            const float* __restrict__ c, float* __restrict__ o) {
  int i = blockIdx.x * 256 + threadIdx.x;  // grid 12*256 = 3072
  o[i] = i < 1024 ? a[i] : (i < 2048 ? b[i - 1024] : c[i - 2048]);
}

// ---------------------------------------------------------------- mask format detect
// JAX bool mask may arrive as int32 {0,1} or raw 1-byte bools. Read first 2048
// int32 (= 8192 bytes, safe in both modes): packed bytes give values >1 w.h.p.
__global__ void detect_mask(const int* __restrict__ m, int* __restrict__ flag) {
  __shared__ int bad;
  if (threadIdx.x == 0) bad = 0;
  __syncthreads();
  int local = 0;
  for (int i = threadIdx.x; i < 2048; i += 256)
    if ((unsigned)m[i] > 1u) local = 1;
  if (local) atomicOr(&bad, 1);
  __syncthreads();
  if (threadIdx.x == 0) *flag = bad;
}

// ---------------------------------------------------------------- masked softmax (in-place, f16)
__global__ LB256 void softmax_mask(f16* __restrict__ S, const void* __restrict__ maskp,
                                   const int* __restrict__ flag) {
  __shared__ float red[4];
  const long r = blockIdx.x;  // 0..8191 (b*2048+q)
  const int b = (int)(r >> 11);
  f16* row = S + r * 2048;
  const int tid = threadIdx.x;
  const bool bytemode = (*flag != 0);
  const int* m32 = (const int*)maskp + (long)b * 2048;
  const unsigned char* m8 = (const unsigned char*)maskp + (long)b * 2048;

  float v[8];
  float mx = -3.0e38f;
#pragma unroll
  for (int it = 0; it < 8; ++it) {
    int k = tid + it * 256;
    bool ok = bytemode ? (m8[k] != 0) : (m32[k] != 0);
    float s = ok ? (float)row[k] : -3.0e38f;
    v[it] = s;
    mx = fmaxf(mx, s);
  }
#pragma unroll
  for (int off = 32; off > 0; off >>= 1) mx = fmaxf(mx, __shfl_xor(mx, off, 64));
  if ((tid & 63) == 0) red[tid >> 6] = mx;
  __syncthreads();
  mx = fmaxf(fmaxf(red[0], red[1]), fmaxf(red[2], red[3]));
  __syncthreads();

  float e[8];
  float sum = 0.f;
#pragma unroll
  for (int it = 0; it < 8; ++it) {
    float ev = (v[it] <= -1.0e38f) ? 0.f : __expf(v[it] - mx);
    e[it] = ev;
    sum += ev;
  }
#pragma unroll
  for (int off = 32; off > 0; off >>= 1) sum += __shfl_xor(sum, off, 64);
  if ((tid & 63) == 0) red[tid >> 6] = sum;
  __syncthreads();
  sum = red[0] + red[1] + red[2] + red[3];
  const float inv = 1.f / sum;
#pragma unroll
  for (int it = 0; it < 8; ++it) {
    int k = tid + it * 256;
    row[k] = (f16)(e[it] * inv);
  }
}

// ---------------------------------------------------------------- V transpose
// Vt[b][d][s] = QKV[b*2048+s][2048+d], so PV is an NT GEMM.
__global__ LB256 void transpose_v(const f16* __restrict__ QKV, f16* __restrict__ Vt) {
  __shared__ f16 t[32][33];
  const int b = blockIdx.z;
  const int d0 = blockIdx.x * 32;
  const int s0 = blockIdx.y * 32;
  const int tx = threadIdx.x & 31;
  const int ty = threadIdx.x >> 5;  // 0..7
  const f16* src = QKV + ((long)(b * 2048 + s0)) * 3072 + 2048;
#pragma unroll
  for (int i = 0; i < 4; ++i)
    t[ty + i * 8][tx] = src[(long)(ty + i * 8) * 3072 + d0 + tx];
  __syncthreads();
  f16* dst = Vt + ((long)b * 1024 + d0) * 2048 + s0;
#pragma unroll
  for (int i = 0; i < 4; ++i)
    dst[(long)(ty + i * 8) * 2048 + tx] = t[tx][ty + i * 8];
}

// ---------------------------------------------------------------- launch
extern "C" void kernel_launch(void* const* d_in, const int* in_sizes, int n_in,
                              void* d_out, int out_size, void* d_ws, size_t ws_size,
                              hipStream_t stream) {
  const float* x = (const float*)d_in[0];
  const void* mask = d_in[1];
  const float* Wq = (const float*)d_in[2];
  const float* bq = (const float*)d_in[3];
  const float* Wk = (const float*)d_in[4];
  const float* bk = (const float*)d_in[5];
  const float* Wv = (const float*)d_in[6];
  const float* bv = (const float*)d_in[7];
  float* out = (float*)d_out;

  // Workspace layout (f16 elements unless noted); total ~118 MB.
  f16* xh = (f16*)d_ws;                  //  8192*1024 = 8388608   (16 MB)
  f16* Wh = xh + 8388608;                //  3072*1024 = 3145728   ( 6 MB)
  f16* QKVh = Wh + 3145728;              //  8192*3072 = 25165824  (48 MB)
  f16* Vt = QKVh + 25165824;             //  4*1024*2048 = 8388608 (16 MB)
  f16* Sbuf = Vt + 8388608;              //  4*2048*2048 = 16777216(32 MB)
  float* bias_cat = (float*)(Sbuf + 16777216);  // 3072 fp32
  int* flag = (int*)(bias_cat + 3072);

  detect_mask<<<1, 256, 0, stream>>>((const int*)mask, flag);
  f32_to_f16_x4<<<8192, 256, 0, stream>>>(x, xh, 8388608L);
  f32_to_f16_x4<<<1024, 256, 0, stream>>>(Wq, Wh, 1048576L);
  f32_to_f16_x4<<<1024, 256, 0, stream>>>(Wk, Wh + 1048576, 1048576L);
  f32_to_f16_x4<<<1024, 256, 0, stream>>>(Wv, Wh + 2097152, 1048576L);
  concat_bias<<<12, 256, 0, stream>>>(bq, bk, bv, bias_cat);

  // QKV = xh @ Wh^T + bias : M=8192, N=3072, K=1024
  gemm_nt<f16><<<dim3(24, 64, 1), 256, 0, stream>>>(
      xh, 1024, 0L, Wh, 1024, 0L, QKVh, 3072, 0L, bias_cat, 1.0f, 1024);

  transpose_v<<<dim3(32, 64, 4), 256, 0, stream>>>(QKVh, Vt);

  // S = (Q @ K^T) / 32 : per batch M=N=2048, K=1024
  gemm_nt<f16><<<dim3(16, 16, 4), 256, 0, stream>>>(
      QKVh, 3072, 2048L * 3072, QKVh + 1024, 3072, 2048L * 3072,
      Sbuf, 2048, 2048L * 2048, nullptr, 0.03125f, 1024);

  softmax_mask<<<8192, 256, 0, stream>>>(Sbuf, mask, flag);

  // O = P @ V = P @ Vt^T : per batch M=2048, N=1024, K=2048
  gemm_nt<float><<<dim3(8, 16, 4), 256, 0, stream>>>(
      Sbuf, 2048, 2048L * 2048, Vt, 2048, 1024L * 2048,
      out, 1024, 2048L * 1024, nullptr, 1.0f, 2048);
}

// Round 2
// 296.525 us; speedup vs baseline: 1.1904x; 1.1904x over previous
//
#include <hip/hip_runtime.h>

// Fused attention: Q/K/V = x@W^T + b (fp16 MFMA), S = mask(QK^T/32), P = softmax(S), O = P@V.
// B=4, S=2048, D=1024 (single head). All GEMMs NT, 128x128 tile, 4 waves, 4x4 16x16x32 MFMA,
// BK=64, global_load_lds width=16, XOR-swizzled LDS layout (conflict-free ds_read_b128):
//   LDS granule slot(r, c) = r*8 + (c ^ (r & 7))   [granule = 16B = 8 f16, row = 64 f16]
// Staging realizes the swizzle by permuting per-lane GLOBAL addresses (LDS dest of
// global_load_lds is hardware-fixed at base + lane*16B, so we permute the source).

typedef _Float16 f16;
typedef _Float16 f16x4 __attribute__((ext_vector_type(4)));
typedef _Float16 f16x8 __attribute__((ext_vector_type(8)));
typedef float f32x4 __attribute__((ext_vector_type(4)));

#define LB256 __launch_bounds__(256)

__device__ __forceinline__ void gld16(const void* gp, void* lp) {
  __builtin_amdgcn_global_load_lds(
      (__attribute__((address_space(1))) void*)(gp),
      (__attribute__((address_space(3))) void*)(lp),
      16, 0, 0);
}

// ---------------------------------------------------------------- NT GEMM
// C[m,n] = scale * sum_k A[m,k]*B[n,k] + bias[n]
// A: [M,K] f16 row-major (lda), B: [N,K] f16 row-major (ldb), C: OutT (ldc).
// Grid: (N/128, M/128, batch). Block: 256. K % 64 == 0.
template <typename OutT>
__global__ __launch_bounds__(256, 4) void gemm_nt(
    const f16* __restrict__ A, int lda, long sA,
    const f16* __restrict__ B, int ldb, long sB,
    OutT* __restrict__ C, int ldc, long sC,
    const float* __restrict__ bias, float scale, int K) {
  __shared__ __align__(16) f16 As[128 * 64];
  __shared__ __align__(16) f16 Bs[128 * 64];
  A += (long)blockIdx.z * sA;
  B += (long)blockIdx.z * sB;
  C += (long)blockIdx.z * sC;
  const int m0 = blockIdx.y * 128;
  const int n0 = blockIdx.x * 128;
  const int tid = threadIdx.x;
  const int w = tid >> 6, l = tid & 63;
  const int wm = (w >> 1) * 64;  // wave row offset in tile
  const int wn = (w & 1) * 64;   // wave col offset in tile
  const int quad = l >> 4, lo = l & 15;

  // Staging: chunk c8 covers rows [c8*8, c8*8+8). Lane l owns LDS slot l of the
  // chunk; the global granule living there is (row rl = l>>3, col cg = (l&7)^rl).
  const int rl = l >> 3;
  const int cg = (l & 7) ^ (rl & 7);
  const int scol = cg * 8;  // f16 col offset of fetched granule

  // Fragment-read swizzle: element (row r, granule c) is at r*64 + (c ^ (r&7))*8.
  // For c = ks*4+quad, r = (16-mult)+lo:  (c^(lo&7))*8 = swz + (ks ? 32-ks0 : ks0).
  const int swz = (quad ^ (lo & 3)) * 8;
  const int ks0 = ((lo >> 2) & 1) * 32;

  f32x4 acc[4][4] = {};

  for (int kk = 0; kk < K; kk += 64) {
#pragma unroll
    for (int r = 0; r < 4; ++r) {
      const int c8 = r * 4 + w;
      const int row = c8 * 8 + rl;
      gld16(A + (long)(m0 + row) * lda + kk + scol, &As[c8 * 512]);
      gld16(B + (long)(n0 + row) * ldb + kk + scol, &Bs[c8 * 512]);
    }
    __syncthreads();
#pragma unroll
    for (int ks = 0; ks < 2; ++ks) {
      const int kso = ks ? (32 - ks0) : ks0;
      f16x8 af[4], bf[4];
#pragma unroll
      for (int i = 0; i < 4; ++i)
        af[i] = *(const f16x8*)&As[(wm + i * 16 + lo) * 64 + swz + kso];
#pragma unroll
      for (int j = 0; j < 4; ++j)
        bf[j] = *(const f16x8*)&Bs[(wn + j * 16 + lo) * 64 + swz + kso];
#pragma unroll
      for (int i = 0; i < 4; ++i)
#pragma unroll
        for (int j = 0; j < 4; ++j)
          acc[i][j] = __builtin_amdgcn_mfma_f32_16x16x32_f16(af[i], bf[j],
                                                             acc[i][j], 0, 0, 0);
    }
    __syncthreads();
  }
  // Epilogue: C/D layout col=lane&15, row=quad*4+reg (m89-verified).
#pragma unroll
  for (int i = 0; i < 4; ++i) {
    const int rowb = m0 + wm + i * 16 + quad * 4;
#pragma unroll
    for (int j = 0; j < 4; ++j) {
      const int col = n0 + wn + j * 16 + lo;
      const float bv = bias ? bias[col] : 0.0f;
#pragma unroll
      for (int r = 0; r < 4; ++r)
        C[(long)(rowb + r) * ldc + col] = (OutT)(acc[i][j][r] * scale + bv);
    }
  }
}

// ---------------------------------------------------------------- fused casts
// Covers x (8388608 f32) then Wq|Wk|Wv (1048576 each) -> xh, Wh (q,k,v packed).
__global__ LB256 void cast_all(const float* __restrict__ x,
                               const float* __restrict__ wq,
                               const float* __restrict__ wk,
                               const float* __restrict__ wv,
                               f16* __restrict__ xh, f16* __restrict__ wh) {
  long i = ((long)blockIdx.x * 256 + threadIdx.x) * 4;
  const float* src;
  f16* dst;
  if (i < 8388608L) {
    src = x + i;
    dst = xh + i;
  } else {
    long j = i - 8388608L;
    int which = (int)(j >> 20);
    const float* ws = which == 0 ? wq : (which == 1 ? wk : wv);
    src = ws + (j & 1048575L);
    dst = wh + j;
  }
  float4 v = *(const float4*)src;
  f16x4 o;
  o[0] = (f16)v.x; o[1] = (f16)v.y; o[2] = (f16)v.z; o[3] = (f16)v.w;
  *(f16x4*)dst = o;
}

// ---------------------------------------------------------------- small fused: bias concat + mask-format detect
// Blocks 0..11: bias concat (3072 floats). Block 12: detect mask int32 vs byte.
__global__ void small_setup(const float* __restrict__ a, const float* __restrict__ b,
                            const float* __restrict__ c, float* __restrict__ o,
                            const int* __restrict__ m, int* __restrict__ flag) {
  if (blockIdx.x < 12) {
    int i = blockIdx.x * 256 + threadIdx.x;
    o[i] = i < 1024 ? a[i] : (i < 2048 ? b[i - 1024] : c[i - 2048]);
  } else {
    __shared__ int bad;
    if (threadIdx.x == 0) bad = 0;
    __syncthreads();
    int local = 0;
    for (int i = threadIdx.x; i < 2048; i += 256)
      if ((unsigned)m[i] > 1u) local = 1;
    if (local) atomicOr(&bad, 1);
    __syncthreads();
    if (threadIdx.x == 0) *flag = bad;
  }
}

// ---------------------------------------------------------------- masked softmax (in-place, f16, vectorized)
__global__ LB256 void softmax_mask(f16* __restrict__ S, const void* __restrict__ maskp,
                                   const int* __restrict__ flag) {
  __shared__ float red[4];
  const long r = blockIdx.x;  // 0..8191 (b*2048+q)
  const int b = (int)(r >> 11);
  f16* row = S + r * 2048;
  const int t = threadIdx.x;  // handles cols t*8 .. t*8+7
  const bool bytemode = (*flag != 0);
  const int* m32 = (const int*)maskp + (long)b * 2048 + t * 8;
  const unsigned char* m8 = (const unsigned char*)maskp + (long)b * 2048 + t * 8;

  f16x8 sv = *(const f16x8*)(row + t * 8);
  float v[8];
  float mx = -3.0e38f;
#pragma unroll
  for (int e = 0; e < 8; ++e) {
    bool ok = bytemode ? (m8[e] != 0) : (m32[e] != 0);
    float s = ok ? (float)sv[e] : -3.0e38f;
    v[e] = s;
    mx = fmaxf(mx, s);
  }
#pragma unroll
  for (int off = 32; off > 0; off >>= 1) mx = fmaxf(mx, __shfl_xor(mx, off, 64));
  if ((t & 63) == 0) red[t >> 6] = mx;
  __syncthreads();
  mx = fmaxf(fmaxf(red[0], red[1]), fmaxf(red[2], red[3]));
  __syncthreads();

  float e[8];
  float sum = 0.f;
#pragma unroll
  for (int it = 0; it < 8; ++it) {
    float ev = (v[it] <= -1.0e38f) ? 0.f : __expf(v[it] - mx);
    e[it] = ev;
    sum += ev;
  }
#pragma unroll
  for (int off = 32; off > 0; off >>= 1) sum += __shfl_xor(sum, off, 64);
  if ((t & 63) == 0) red[t >> 6] = sum;
  __syncthreads();
  sum = red[0] + red[1] + red[2] + red[3];
  const float inv = 1.f / sum;
  f16x8 ov;
#pragma unroll
  for (int it = 0; it < 8; ++it) ov[it] = (f16)(e[it] * inv);
  *(f16x8*)(row + t * 8) = ov;
}

// ---------------------------------------------------------------- V transpose
// Vt[b][d][s] = QKV[b*2048+s][2048+d], so PV is an NT GEMM.
__global__ LB256 void transpose_v(const f16* __restrict__ QKV, f16* __restrict__ Vt) {
  __shared__ f16 t[32][33];
  const int b = blockIdx.z;
  const int d0 = blockIdx.x * 32;
  const int s0 = blockIdx.y * 32;
  const int tx = threadIdx.x & 31;
  const int ty = threadIdx.x >> 5;  // 0..7
  const f16* src = QKV + ((long)(b * 2048 + s0)) * 3072 + 2048;
#pragma unroll
  for (int i = 0; i < 4; ++i)
    t[ty + i * 8][tx] = src[(long)(ty + i * 8) * 3072 + d0 + tx];
  __syncthreads();
  f16* dst = Vt + ((long)b * 1024 + d0) * 2048 + s0;
#pragma unroll
  for (int i = 0; i < 4; ++i)
    dst[(long)(ty + i * 8) * 2048 + tx] = t[tx][ty + i * 8];
}

// ---------------------------------------------------------------- launch
extern "C" void kernel_launch(void* const* d_in, const int* in_sizes, int n_in,
                              void* d_out, int out_size, void* d_ws, size_t ws_size,
                              hipStream_t stream) {
  const float* x = (const float*)d_in[0];
  const void* mask = d_in[1];
  const float* Wq = (const float*)d_in[2];
  const float* bq = (const float*)d_in[3];
  const float* Wk = (const float*)d_in[4];
  const float* bk = (const float*)d_in[5];
  const float* Wv = (const float*)d_in[6];
  const float* bv = (const float*)d_in[7];
  float* out = (float*)d_out;

  // Workspace layout (f16 elements unless noted); total ~118 MB.
  f16* xh = (f16*)d_ws;                  //  8192*1024 = 8388608   (16 MB)
  f16* Wh = xh + 8388608;                //  3072*1024 = 3145728   ( 6 MB)
  f16* QKVh = Wh + 3145728;              //  8192*3072 = 25165824  (48 MB)
  f16* Vt = QKVh + 25165824;             //  4*1024*2048 = 8388608 (16 MB)
  f16* Sbuf = Vt + 8388608;              //  4*2048*2048 = 16777216(32 MB)
  float* bias_cat = (float*)(Sbuf + 16777216);  // 3072 fp32
  int* flag = (int*)(bias_cat + 3072);

  cast_all<<<11264, 256, 0, stream>>>(x, Wq, Wk, Wv, xh, Wh);
  small_setup<<<13, 256, 0, stream>>>(bq, bk, bv, bias_cat, (const int*)mask, flag);

  // QKV = xh @ Wh^T + bias : M=8192, N=3072, K=1024
  gemm_nt<f16><<<dim3(24, 64, 1), 256, 0, stream>>>(
      xh, 1024, 0L, Wh, 1024, 0L, QKVh, 3072, 0L, bias_cat, 1.0f, 1024);

  transpose_v<<<dim3(32, 64, 4), 256, 0, stream>>>(QKVh, Vt);

  // S = (Q @ K^T) / 32 : per batch M=N=2048, K=1024
  gemm_nt<f16><<<dim3(16, 16, 4), 256, 0, stream>>>(
      QKVh, 3072, 2048L * 3072, QKVh + 1024, 3072, 2048L * 3072,
      Sbuf, 2048, 2048L * 2048, nullptr, 0.03125f, 1024);

  softmax_mask<<<8192, 256, 0, stream>>>(Sbuf, mask, flag);

  // O = P @ V = P @ Vt^T : per batch M=2048, N=1024, K=2048
  gemm_nt<float><<<dim3(8, 16, 4), 256, 0, stream>>>(
      Sbuf, 2048, 2048L * 2048, Vt, 2048, 1024L * 2048,
      out, 1024, 2048L * 1024, nullptr, 1.0f, 2048);
}

// Round 3
// 251.401 us; speedup vs baseline: 1.4041x; 1.1795x over previous
//
#include <hip/hip_runtime.h>

// Fused attention with masked-key compaction.
// Q = x@Wq^T+bq (all 8192 rows); K,V computed only for VALID keys (mask ~halves them).
// S = (Q Kc^T)/32 over compacted cols, softmax (pad cols -inf), O = P @ Vc.
// GEMM: 128x128 tile, 4 waves, 4x4 16x16x32 f16 MFMA, BK=64, global_load_lds w=16,
// XOR-swizzled LDS (conflict-free ds_read_b128, verified R2: SQ_LDS_BANK_CONFLICT=0),
// plus per-batch runtime m/n/k limits (uniform early-exit / loop bound).

typedef _Float16 f16;
typedef _Float16 f16x4 __attribute__((ext_vector_type(4)));
typedef _Float16 f16x8 __attribute__((ext_vector_type(8)));
typedef float f32x4 __attribute__((ext_vector_type(4)));

#define LB256 __launch_bounds__(256)

__device__ __forceinline__ void gld16(const void* gp, void* lp) {
  __builtin_amdgcn_global_load_lds(
      (__attribute__((address_space(1))) void*)(gp),
      (__attribute__((address_space(3))) void*)(lp),
      16, 0, 0);
}

// ---------------------------------------------------------------- NT GEMM
// C[m,n] = scale * sum_k A[m,k]*B[n,k] + bias(n)
// mlim/nlim: per-batch tile early-exit; klim: per-batch K bound (mult of 64).
template <typename OutT>
__global__ __launch_bounds__(256, 4) void gemm_nt(
    const f16* __restrict__ A, int lda, long sA,
    const f16* __restrict__ B, int ldb, long sB,
    OutT* __restrict__ C, int ldc, long sC,
    const float* __restrict__ bias1, const float* __restrict__ bias2, int nb1,
    float scale, int K,
    const int* __restrict__ mlim, const int* __restrict__ nlim,
    const int* __restrict__ klim) {
  const int m0 = blockIdx.y * 128;
  const int n0 = blockIdx.x * 128;
  const int z = blockIdx.z;
  if (mlim && m0 >= mlim[z]) return;
  if (nlim && n0 >= nlim[z]) return;
  const int Ke = klim ? klim[z] : K;

  __shared__ __align__(16) f16 As[128 * 64];
  __shared__ __align__(16) f16 Bs[128 * 64];
  A += (long)z * sA;
  B += (long)z * sB;
  C += (long)z * sC;
  const int tid = threadIdx.x;
  const int w = tid >> 6, l = tid & 63;
  const int wm = (w >> 1) * 64;
  const int wn = (w & 1) * 64;
  const int quad = l >> 4, lo = l & 15;

  // Staging: chunk c8 covers rows [c8*8, c8*8+8). Lane l owns LDS slot l; global
  // granule there is (row rl=l>>3, col cg=(l&7)^rl) -> XOR-swizzled LDS layout.
  const int rl = l >> 3;
  const int cg = (l & 7) ^ (rl & 7);
  const int scol = cg * 8;

  // Fragment read: element (r, granule c) at r*64 + (c^(r&7))*8.
  const int swz = (quad ^ (lo & 3)) * 8;
  const int ks0 = ((lo >> 2) & 1) * 32;

  f32x4 acc[4][4] = {};

  for (int kk = 0; kk < Ke; kk += 64) {
#pragma unroll
    for (int r = 0; r < 4; ++r) {
      const int c8 = r * 4 + w;
      const int row = c8 * 8 + rl;
      gld16(A + (long)(m0 + row) * lda + kk + scol, &As[c8 * 512]);
      gld16(B + (long)(n0 + row) * ldb + kk + scol, &Bs[c8 * 512]);
    }
    __syncthreads();
#pragma unroll
    for (int ks = 0; ks < 2; ++ks) {
      const int kso = ks ? (32 - ks0) : ks0;
      f16x8 af[4], bf[4];
#pragma unroll
      for (int i = 0; i < 4; ++i)
        af[i] = *(const f16x8*)&As[(wm + i * 16 + lo) * 64 + swz + kso];
#pragma unroll
      for (int j = 0; j < 4; ++j)
        bf[j] = *(const f16x8*)&Bs[(wn + j * 16 + lo) * 64 + swz + kso];
#pragma unroll
      for (int i = 0; i < 4; ++i)
#pragma unroll
        for (int j = 0; j < 4; ++j)
          acc[i][j] = __builtin_amdgcn_mfma_f32_16x16x32_f16(af[i], bf[j],
                                                             acc[i][j], 0, 0, 0);
    }
    __syncthreads();
  }
  // Epilogue: C/D layout col=lane&15, row=quad*4+reg.
#pragma unroll
  for (int i = 0; i < 4; ++i) {
    const int rowb = m0 + wm + i * 16 + quad * 4;
#pragma unroll
    for (int j = 0; j < 4; ++j) {
      const int col = n0 + wn + j * 16 + lo;
      float bv = 0.f;
      if (bias1) bv = (col < nb1) ? bias1[col] : bias2[col - nb1];
#pragma unroll
      for (int r = 0; r < 4; ++r)
        C[(long)(rowb + r) * ldc + col] = (OutT)(acc[i][j][r] * scale + bv);
    }
  }
}

// ---------------------------------------------------------------- fused casts
__global__ LB256 void cast_all(const float* __restrict__ x,
                               const float* __restrict__ wq,
                               const float* __restrict__ wk,
                               const float* __restrict__ wv,
                               f16* __restrict__ xh, f16* __restrict__ wh) {
  long i = ((long)blockIdx.x * 256 + threadIdx.x) * 4;
  const float* src;
  f16* dst;
  if (i < 8388608L) {
    src = x + i;
    dst = xh + i;
  } else {
    long j = i - 8388608L;
    int which = (int)(j >> 20);
    const float* ws = which == 0 ? wq : (which == 1 ? wk : wv);
    src = ws + (j & 1048575L);
    dst = wh + j;
  }
  float4 v = *(const float4*)src;
  f16x4 o;
  o[0] = (f16)v.x; o[1] = (f16)v.y; o[2] = (f16)v.z; o[3] = (f16)v.w;
  *(f16x4*)dst = o;
}

// ---------------------------------------------------------------- mask scan
// One block per batch. Detects int32-vs-byte mask format (first 2048 int32 = 8KB,
// safe in both modes), then prefix-sums the batch's 2048 mask bits into
// sel[b][s'] (valid key indices, ascending), counts[b], npad[b] (round-up 128).
__global__ void scan_mask(const void* __restrict__ maskp, int* __restrict__ sel,
                          int* __restrict__ counts, int* __restrict__ npad) {
  const int b = blockIdx.x;
  const int t = threadIdx.x;
  __shared__ int bad;
  __shared__ int s[256];
  if (t == 0) bad = 0;
  __syncthreads();
  const int* mi = (const int*)maskp;
  int loc = 0;
  for (int i = t; i < 2048; i += 256)
    if ((unsigned)mi[i] > 1u) loc = 1;
  if (loc) atomicOr(&bad, 1);
  __syncthreads();
  const bool bytemode = bad != 0;

  int m[8];
  if (bytemode) {
    const unsigned char* p = (const unsigned char*)maskp + b * 2048 + t * 8;
#pragma unroll
    for (int e = 0; e < 8; ++e) m[e] = p[e] != 0;
  } else {
    const int* p = mi + b * 2048 + t * 8;
#pragma unroll
    for (int e = 0; e < 8; ++e) m[e] = p[e] != 0;
  }
  int local = 0;
#pragma unroll
  for (int e = 0; e < 8; ++e) local += m[e];
  s[t] = local;
  __syncthreads();
  for (int off = 1; off < 256; off <<= 1) {
    int v = (t >= off) ? s[t - off] : 0;
    __syncthreads();
    s[t] += v;
    __syncthreads();
  }
  int offp = s[t] - local;  // exclusive prefix
#pragma unroll
  for (int e = 0; e < 8; ++e)
    if (m[e]) sel[b * 2048 + offp++] = t * 8 + e;
  if (t == 0) {
    counts[b] = s[255];
    npad[b] = ((s[255] + 127) >> 7) << 7;
  }
}

// ---------------------------------------------------------------- gather valid x rows
// xc[b][s'][:] = xh[b][sel[s']][:] for s'<counts; zeros for s' in [counts, npad).
__global__ LB256 void gather_x(const f16* __restrict__ xh, const int* __restrict__ sel,
                               const int* __restrict__ counts,
                               const int* __restrict__ npad, f16* __restrict__ xc) {
  const int b = blockIdx.y;
  const int sp = blockIdx.x;
  if (sp >= npad[b]) return;
  const int t = threadIdx.x;
  f16* dst = xc + ((long)b * 2048 + sp) * 1024;
  if (sp >= counts[b]) {
    *(f16x4*)(dst + t * 4) = (f16x4){0, 0, 0, 0};
    return;
  }
  const f16* src = xh + ((long)b * 2048 + sel[b * 2048 + sp]) * 1024;
  *(f16x4*)(dst + t * 4) = *(const f16x4*)(src + t * 4);
}

// ---------------------------------------------------------------- compacted softmax
// Row r=b*2048+q. Cols < counts[b]: real; [counts, npad): -inf -> writes 0;
// >= npad: untouched (never read downstream; PV k-loop stops at npad).
__global__ LB256 void softmax_c(f16* __restrict__ S, const int* __restrict__ counts,
                                const int* __restrict__ npad) {
  __shared__ float red[4];
  const long r = blockIdx.x;
  const int b = (int)(r >> 11);
  const int nv = counts[b], np = npad[b];
  f16* row = S + r * 2048;
  const int t = threadIdx.x;
  const bool act = (t * 8) < np;

  float v[8];
  float mx = -3.0e38f;
  if (act) {
    f16x8 sv = *(const f16x8*)(row + t * 8);
#pragma unroll
    for (int e = 0; e < 8; ++e) {
      float s = (t * 8 + e < nv) ? (float)sv[e] : -3.0e38f;
      v[e] = s;
      mx = fmaxf(mx, s);
    }
  } else {
#pragma unroll
    for (int e = 0; e < 8; ++e) v[e] = -3.0e38f;
  }
#pragma unroll
  for (int off = 32; off > 0; off >>= 1) mx = fmaxf(mx, __shfl_xor(mx, off, 64));
  if ((t & 63) == 0) red[t >> 6] = mx;
  __syncthreads();
  mx = fmaxf(fmaxf(red[0], red[1]), fmaxf(red[2], red[3]));
  __syncthreads();

  float e[8];
  float sum = 0.f;
#pragma unroll
  for (int it = 0; it < 8; ++it) {
    float ev = (v[it] <= -1.0e38f) ? 0.f : __expf(v[it] - mx);
    e[it] = ev;
    sum += ev;
  }
#pragma unroll
  for (int off = 32; off > 0; off >>= 1) sum += __shfl_xor(sum, off, 64);
  if ((t & 63) == 0) red[t >> 6] = sum;
  __syncthreads();
  sum = red[0] + red[1] + red[2] + red[3];
  if (act) {
    const float inv = 1.f / sum;
    f16x8 ov;
#pragma unroll
    for (int it = 0; it < 8; ++it) ov[it] = (f16)(e[it] * inv);
    *(f16x8*)(row + t * 8) = ov;
  }
}

// ---------------------------------------------------------------- V transpose (compacted)
// Vtc[b][d][s'] = KVc[b][s'][1024+d], s' < npad[b].
__global__ LB256 void transpose_v(const f16* __restrict__ KVc, f16* __restrict__ Vtc,
                                  const int* __restrict__ npad) {
  const int b = blockIdx.z;
  const int s0 = blockIdx.y * 32;
  if (s0 >= npad[b]) return;
  __shared__ f16 t[32][33];
  const int d0 = blockIdx.x * 32;
  const int tx = threadIdx.x & 31;
  const int ty = threadIdx.x >> 5;  // 0..7
  const f16* src = KVc + ((long)b * 2048 + s0) * 2048 + 1024;
#pragma unroll
  for (int i = 0; i < 4; ++i)
    t[ty + i * 8][tx] = src[(long)(ty + i * 8) * 2048 + d0 + tx];
  __syncthreads();
  f16* dst = Vtc + ((long)b * 1024 + d0) * 2048 + s0;
#pragma unroll
  for (int i = 0; i < 4; ++i)
    dst[(long)(ty + i * 8) * 2048 + tx] = t[tx][ty + i * 8];
}

// ---------------------------------------------------------------- launch
extern "C" void kernel_launch(void* const* d_in, const int* in_sizes, int n_in,
                              void* d_out, int out_size, void* d_ws, size_t ws_size,
                              hipStream_t stream) {
  const float* x = (const float*)d_in[0];
  const void* mask = d_in[1];
  const float* Wq = (const float*)d_in[2];
  const float* bq = (const float*)d_in[3];
  const float* Wk = (const float*)d_in[4];
  const float* bk = (const float*)d_in[5];
  const float* Wv = (const float*)d_in[6];
  const float* bv = (const float*)d_in[7];
  float* out = (float*)d_out;

  // Workspace (f16 elems). Sbuf aliases [xh|xc] (both dead before scores GEMM).
  f16* xh = (f16*)d_ws;            // 8M  (16 MB)
  f16* xc = xh + 8388608;          // 8M  (16 MB) compacted x, stride 2048 rows/batch
  f16* Sbuf = xh;                  // 16M (32 MB) alias
  f16* Wh = xc + 8388608;          // 3M  (6 MB)  [Wq|Wk|Wv]
  f16* Qb = Wh + 3145728;          // 8M  (16 MB)
  f16* KVc = Qb + 8388608;         // 16M (32 MB) [K|V] compacted, stride 2048 rows
  f16* Vtc = KVc + 16777216;       // 8M  (16 MB)
  int* sel = (int*)(Vtc + 8388608);  // 8192 ints
  int* counts = sel + 8192;          // 4
  int* npad = counts + 4;            // 4

  cast_all<<<11264, 256, 0, stream>>>(x, Wq, Wk, Wv, xh, Wh);
  scan_mask<<<4, 256, 0, stream>>>(mask, sel, counts, npad);
  gather_x<<<dim3(2048, 4), 256, 0, stream>>>(xh, sel, counts, npad, xc);

  // Q = xh @ Wq^T + bq : M=8192, N=1024, K=1024
  gemm_nt<f16><<<dim3(8, 64, 1), 256, 0, stream>>>(
      xh, 1024, 0L, Wh, 1024, 0L, Qb, 1024, 0L,
      bq, bq, 1 << 30, 1.0f, 1024, nullptr, nullptr, nullptr);

  // [Kc|Vc] = xc @ [Wk|Wv]^T + [bk|bv] : per batch M=npad[b], N=2048, K=1024
  gemm_nt<f16><<<dim3(16, 16, 4), 256, 0, stream>>>(
      xc, 1024, 2048L * 1024, Wh + 1048576, 1024, 0L, KVc, 2048, 2048L * 2048,
      bk, bv, 1024, 1.0f, 1024, npad, nullptr, nullptr);

  transpose_v<<<dim3(32, 64, 4), 256, 0, stream>>>(KVc, Vtc, npad);

  // S = (Q @ Kc^T)/32 : per batch M=2048, N=npad[b], K=1024
  gemm_nt<f16><<<dim3(16, 16, 4), 256, 0, stream>>>(
      Qb, 1024, 2048L * 1024, KVc, 2048, 2048L * 2048,
      Sbuf, 2048, 2048L * 2048, nullptr, nullptr, 0, 0.03125f, 1024,
      nullptr, npad, nullptr);

  softmax_c<<<8192, 256, 0, stream>>>(Sbuf, counts, npad);

  // O = P @ Vtc^T : per batch M=2048, N=1024, K=npad[b]
  gemm_nt<float><<<dim3(8, 16, 4), 256, 0, stream>>>(
      Sbuf, 2048, 2048L * 2048, Vtc, 2048, 1024L * 2048,
      out, 1024, 2048L * 1024, nullptr, nullptr, 0, 1.0f, 2048,
      nullptr, nullptr, npad);
}